// Round 1
// baseline (618.657 us; speedup 1.0000x reference)
//
#include <hip/hip_runtime.h>
#include <hip/hip_bf16.h>

#define DEV __device__ __forceinline__

typedef unsigned short u16;
typedef __attribute__((ext_vector_type(4))) float f32x4;
typedef __attribute__((ext_vector_type(8))) short s16x8;

// problem constants
static constexpr int Bc = 2, Hc = 16, Sc = 4096, Dc = 1024, HDc = 64;

DEV u16 f2bf(float f) {
  unsigned x = __float_as_uint(f);
  x += 0x7FFFu + ((x >> 16) & 1u);   // RNE
  return (u16)(x >> 16);
}
DEV float bf2f(u16 u) { return __uint_as_float(((unsigned)u) << 16); }

DEV void gload_lds16(const void* g, void* l) {
  __builtin_amdgcn_global_load_lds((const __attribute__((address_space(1))) void*)g,
                                   (__attribute__((address_space(3))) void*)l, 16, 0, 0);
}

DEV f32x4 mfma16(s16x8 a, s16x8 b, f32x4 c) {
  return __builtin_amdgcn_mfma_f32_16x16x32_bf16(a, b, c, 0, 0, 0);
}

DEV f32x4 fzero4() { f32x4 v; v[0] = v[1] = v[2] = v[3] = 0.f; return v; }

// ---------------- elementwise f32 -> bf16 ----------------
__global__ void cvt_f32_bf16(const float* __restrict__ in, u16* __restrict__ out, size_t n) {
  size_t i = ((size_t)blockIdx.x * blockDim.x + threadIdx.x) * 4;
  size_t stride = (size_t)gridDim.x * blockDim.x * 4;
  for (; i < n; i += stride) {
    float4 v = *(const float4*)(in + i);
    u16 a = f2bf(v.x), b = f2bf(v.y), c = f2bf(v.z), d = f2bf(v.w);
    *(ushort4*)(out + i) = make_ushort4(a, b, c, d);
  }
}

// ---------------- transpose + convert: out[c][r] = bf16(in[r][c]) ----------------
__global__ void transpose_cvt(const float* __restrict__ in, u16* __restrict__ out, int R, int C) {
  __shared__ u16 t[64][72];
  int nct = C >> 6;
  int tr = blockIdx.x / nct, tc = blockIdx.x % nct;
  int r0 = tr << 6, c0 = tc << 6;
  int lr = threadIdx.x >> 2;
  int lc0 = (threadIdx.x & 3) << 4;
  const float* src = in + (size_t)(r0 + lr) * C + c0 + lc0;
#pragma unroll
  for (int j = 0; j < 16; j += 4) {
    float4 v = *(const float4*)(src + j);
    t[lr][lc0 + j + 0] = f2bf(v.x);
    t[lr][lc0 + j + 1] = f2bf(v.y);
    t[lr][lc0 + j + 2] = f2bf(v.z);
    t[lr][lc0 + j + 3] = f2bf(v.w);
  }
  __syncthreads();
  u16* dst = out + (size_t)(c0 + lr) * R + r0 + lc0;
#pragma unroll
  for (int j = 0; j < 16; j += 4) {
    u16 a = t[lc0 + j + 0][lr], b = t[lc0 + j + 1][lr], c = t[lc0 + j + 2][lr], d = t[lc0 + j + 3][lr];
    *(ushort4*)(dst + j) = make_ushort4(a, b, c, d);
  }
}

// ---------------- GEMM: C[m][n] = A[m][:] . BT[n][:] + bias[n] ----------------
// A [M][K] bf16 row-major, BT [N][K] bf16 row-major. 128x128 tile, BK=64,
// 256 threads = 4 waves (2x2 of 64x64). LDS XOR-8 swizzle, global_load_lds w=16.
// MODE 0: QKV scatter epilogue (out0=qb, out1=kb, out2=vT).
// MODE 1: f32 output + bias (out0=float* out).
template <int MODE>
__global__ __launch_bounds__(256, 2) void gemm128(
    const u16* __restrict__ A, const u16* __restrict__ BT, const float* __restrict__ bias,
    void* __restrict__ out0, u16* __restrict__ out1, u16* __restrict__ out2,
    int N, int K, int grid_n) {
  __shared__ u16 Al[128 * 64];
  __shared__ u16 Bl[128 * 64];
  int bid = blockIdx.x;
  int bn = bid % grid_n, bm = bid / grid_n;
  int m0 = bm * 128, n0 = bn * 128;
  int tid = threadIdx.x, lane = tid & 63, wid = tid >> 6;
  int wm = wid >> 1, wn = wid & 1;
  int fr = lane & 15, fg = lane >> 4;

  f32x4 acc[4][4];
#pragma unroll
  for (int mi = 0; mi < 4; ++mi)
#pragma unroll
    for (int ni = 0; ni < 4; ++ni) acc[mi][ni] = fzero4();

  for (int kt = 0; kt < K; kt += 64) {
    const u16* Ag = A + (size_t)m0 * K + kt;
    const u16* Bg = BT + (size_t)n0 * K + kt;
#pragma unroll
    for (int it = 0; it < 4; ++it) {
      int L = it * 4096 + wid * 1024 + lane * 16;  // byte offset in 16KB tile
      int row = L >> 7;
      int sch = ((L >> 4) & 7) ^ (row & 7);
      gload_lds16(Ag + (size_t)row * K + sch * 8, (char*)Al + it * 4096 + wid * 1024);
      gload_lds16(Bg + (size_t)row * K + sch * 8, (char*)Bl + it * 4096 + wid * 1024);
    }
    __syncthreads();
#pragma unroll
    for (int c = 0; c < 2; ++c) {
      s16x8 af[4], bfr[4];
#pragma unroll
      for (int mi = 0; mi < 4; ++mi) {
        int row = wm * 64 + mi * 16 + fr;
        int ch = (c * 4 + fg) ^ (row & 7);
        af[mi] = *(const s16x8*)((const char*)Al + row * 128 + ch * 16);
      }
#pragma unroll
      for (int ni = 0; ni < 4; ++ni) {
        int row = wn * 64 + ni * 16 + fr;
        int ch = (c * 4 + fg) ^ (row & 7);
        bfr[ni] = *(const s16x8*)((const char*)Bl + row * 128 + ch * 16);
      }
#pragma unroll
      for (int mi = 0; mi < 4; ++mi)
#pragma unroll
        for (int ni = 0; ni < 4; ++ni) acc[mi][ni] = mfma16(af[mi], bfr[ni], acc[mi][ni]);
    }
    __syncthreads();
  }

  if constexpr (MODE == 0) {
    u16* qb = (u16*)out0;
    u16* kb = out1;
    u16* vT = out2;
#pragma unroll
    for (int ni = 0; ni < 4; ++ni) {
      int n = n0 + wn * 64 + ni * 16 + fr;
      float bv = bias[n];
      int h = n / 192;
      int c = n % 192;
      int part = c >> 6;
      int e = c & 63;
#pragma unroll
      for (int mi = 0; mi < 4; ++mi) {
        int m = m0 + wm * 64 + mi * 16 + fg * 4;
        int b = m >> 12;
        int s = m & 4095;
        size_t bh = (size_t)b * Hc + h;
        if (part == 2) {
          u16 a0 = f2bf(acc[mi][ni][0] + bv), a1 = f2bf(acc[mi][ni][1] + bv);
          u16 a2 = f2bf(acc[mi][ni][2] + bv), a3 = f2bf(acc[mi][ni][3] + bv);
          *(ushort4*)(vT + ((bh * HDc + e) * (size_t)Sc + s)) = make_ushort4(a0, a1, a2, a3);
        } else {
          u16* dst = (part == 0 ? qb : kb) + ((bh * Sc + s) * (size_t)HDc + e);
#pragma unroll
          for (int r = 0; r < 4; ++r) dst[(size_t)r * HDc] = f2bf(acc[mi][ni][r] + bv);
        }
      }
    }
  } else {
    float* O = (float*)out0;
#pragma unroll
    for (int ni = 0; ni < 4; ++ni) {
      int n = n0 + wn * 64 + ni * 16 + fr;
      float bv = bias[n];
#pragma unroll
      for (int mi = 0; mi < 4; ++mi) {
        int m = m0 + wm * 64 + mi * 16 + fg * 4;
#pragma unroll
        for (int r = 0; r < 4; ++r) O[(size_t)(m + r) * N + n] = acc[mi][ni][r] + bv;
      }
    }
  }
}

// ---------------- flash attention ----------------
// grid: 2048 = (qt[64], b[2], h[16]) ; h fastest for mask L2 reuse.
// block: 256 threads = 4 waves, each wave owns 16 q-rows of a 64-row q-tile.
__global__ __launch_bounds__(256, 2) void attn_kernel(
    const u16* __restrict__ qb, const u16* __restrict__ kb, const u16* __restrict__ vT,
    const void* __restrict__ maskp, int mask_is_bf16, u16* __restrict__ vals) {
  __shared__ u16 Kl[64 * 64];
  __shared__ u16 Vl[64 * 64];
  __shared__ u16 Pl[4 * 16 * 64];
  int bid = blockIdx.x;
  int h = bid & 15, b = (bid >> 4) & 1, qt = bid >> 5;
  int lane = threadIdx.x & 63, wid = threadIdx.x >> 6;
  int fr = lane & 15, fg = lane >> 4;
  size_t bh = (size_t)b * Hc + h;
  int q0 = qt * 64;

  // Q fragments (held in registers for the whole kernel)
  const u16* Qrow = qb + ((bh * Sc) + q0 + wid * 16 + fr) * (size_t)HDc;
  s16x8 qa0 = *(const s16x8*)(Qrow);
  s16x8 qa1 = *(const s16x8*)(Qrow + 32);
  // elems (lane>>4)*8 within each 32-chunk:
  qa0 = *(const s16x8*)(Qrow + fg * 8);
  qa1 = *(const s16x8*)(Qrow + 32 + fg * 8);

  f32x4 o[4];
#pragma unroll
  for (int ef = 0; ef < 4; ++ef) o[ef] = fzero4();
  float mrun[4], lrun[4];
#pragma unroll
  for (int r = 0; r < 4; ++r) { mrun[r] = -1e30f; lrun[r] = 0.f; }

  const u16* Kg = kb + bh * (size_t)Sc * HDc;
  const u16* Vg = vT + bh * (size_t)HDc * Sc;
  u16* pw = Pl + wid * 1024;
  const float LOG2E = 1.44269504088896340736f;
  const float SCALE = 0.125f;

  for (int kt = 0; kt < Sc / 64; ++kt) {
    // stage K-tile [64 keys][64 e] and V^T-tile [64 e][64 keys], XOR-8 swizzled
#pragma unroll
    for (int it = 0; it < 2; ++it) {
      int L = it * 4096 + wid * 1024 + lane * 16;
      int row = L >> 7;
      int sch = ((L >> 4) & 7) ^ (row & 7);
      gload_lds16(Kg + ((size_t)(kt * 64 + row)) * HDc + sch * 8, (char*)Kl + it * 4096 + wid * 1024);
      gload_lds16(Vg + (size_t)row * Sc + kt * 64 + sch * 8, (char*)Vl + it * 4096 + wid * 1024);
    }
    __syncthreads();

    // QK^T : sa[f] covers keys [16f,16f+16), q rows fg*4+r
    f32x4 sa[4];
#pragma unroll
    for (int f = 0; f < 4; ++f) sa[f] = fzero4();
#pragma unroll
    for (int c = 0; c < 2; ++c) {
      s16x8 qa = (c == 0) ? qa0 : qa1;
#pragma unroll
      for (int f = 0; f < 4; ++f) {
        int row = f * 16 + fr;
        int ch = (c * 4 + fg) ^ (fr & 7);
        s16x8 kf = *(const s16x8*)((const char*)Kl + row * 128 + ch * 16);
        sa[f] = mfma16(qa, kf, sa[f]);
      }
    }

    // scale + mask
    float sv[4][4];
    {
      int mrow0 = q0 + wid * 16 + fg * 4;
      if (mask_is_bf16) {
        const u16* mk = (const u16*)maskp + ((size_t)(b * Sc + mrow0)) * Sc + (size_t)kt * 64 + fr;
#pragma unroll
        for (int f = 0; f < 4; ++f)
#pragma unroll
          for (int r = 0; r < 4; ++r)
            sv[f][r] = fmaf(sa[f][r], SCALE, bf2f(mk[(size_t)r * Sc + f * 16]));
      } else {
        const float* mk = (const float*)maskp + ((size_t)(b * Sc + mrow0)) * Sc + (size_t)kt * 64 + fr;
#pragma unroll
        for (int f = 0; f < 4; ++f)
#pragma unroll
          for (int r = 0; r < 4; ++r)
            sv[f][r] = fmaf(sa[f][r], SCALE, mk[(size_t)r * Sc + f * 16]);
      }
    }

    // online softmax (per q-row r; row's 64 key-vals live in this 16-lane group)
    float pv[4][4], alph[4];
#pragma unroll
    for (int r = 0; r < 4; ++r) {
      float mt = fmaxf(fmaxf(sv[0][r], sv[1][r]), fmaxf(sv[2][r], sv[3][r]));
#pragma unroll
      for (int d = 1; d < 16; d <<= 1) mt = fmaxf(mt, __shfl_xor(mt, d, 64));
      float mnew = fmaxf(mrun[r], mt);
      alph[r] = exp2f((mrun[r] - mnew) * LOG2E);
      mrun[r] = mnew;
      float ssum = 0.f;
#pragma unroll
      for (int f = 0; f < 4; ++f) {
        float p = exp2f((sv[f][r] - mnew) * LOG2E);
        pv[f][r] = p;
        ssum += p;
      }
#pragma unroll
      for (int d = 1; d < 16; d <<= 1) ssum += __shfl_xor(ssum, d, 64);
      lrun[r] = lrun[r] * alph[r] + ssum;
    }
#pragma unroll
    for (int ef = 0; ef < 4; ++ef)
#pragma unroll
      for (int r = 0; r < 4; ++r) o[ef][r] *= alph[r];

    // P -> LDS (bf16, swizzled), then PV
#pragma unroll
    for (int f = 0; f < 4; ++f)
#pragma unroll
      for (int r = 0; r < 4; ++r) {
        int row = fg * 4 + r;
        int col = f * 16 + fr;
        int byte = row * 128 + ((((col >> 3) ^ (row & 7)) << 4) | ((col & 7) << 1));
        *(u16*)((char*)pw + byte) = f2bf(pv[f][r]);
      }
#pragma unroll
    for (int c = 0; c < 2; ++c) {
      int pch = (c * 4 + fg) ^ (fr & 7);
      s16x8 pa = *(const s16x8*)((const char*)pw + fr * 128 + pch * 16);
#pragma unroll
      for (int ef = 0; ef < 4; ++ef) {
        int row = ef * 16 + fr;
        int ch = (c * 4 + fg) ^ (fr & 7);
        s16x8 vf = *(const s16x8*)((const char*)Vl + row * 128 + ch * 16);
        o[ef] = mfma16(pa, vf, o[ef]);
      }
    }
    __syncthreads();
  }

  // epilogue: normalize + store to vals in [B,H,S,HD]-flat order
  float inv[4];
#pragma unroll
  for (int r = 0; r < 4; ++r) inv[r] = 1.f / lrun[r];
#pragma unroll
  for (int ef = 0; ef < 4; ++ef)
#pragma unroll
    for (int r = 0; r < 4; ++r) {
      int q = q0 + wid * 16 + fg * 4 + r;
      int e = ef * 16 + fr;
      vals[(size_t)b * Sc * Dc + (size_t)h * Sc * HDc + (size_t)q * HDc + e] = f2bf(o[ef][r] * inv[r]);
    }
}

extern "C" void kernel_launch(void* const* d_in, const int* in_sizes, int n_in,
                              void* d_out, int out_size, void* d_ws, size_t ws_size,
                              hipStream_t stream) {
  (void)in_sizes; (void)n_in; (void)out_size;
  const float* x    = (const float*)d_in[0];
  const float* mask = (const float*)d_in[1];
  const float* Wqkv = (const float*)d_in[2];
  const float* bqkv = (const float*)d_in[3];
  const float* Wo   = (const float*)d_in[4];
  const float* bo   = (const float*)d_in[5];
  float* out = (float*)d_out;
  char* ws = (char*)d_ws;

  u16* xb    = (u16*)(ws + 0);          // 16.8 MB   x as bf16 [8192][1024]
  u16* wqkvT = (u16*)(ws + 16777216);   // 6.3 MB    Wqkv^T bf16 [3072][1024]
  u16* woT   = (u16*)(ws + 23068672);   // 2.1 MB    Wo^T bf16 [1024][1024]
  u16* qb    = (u16*)(ws + 25165824);   // 16.8 MB   Q bf16 [B,H,S,64]
  u16* kb    = (u16*)(ws + 41943040);   // 16.8 MB   K bf16 [B,H,S,64]
  u16* vT    = (u16*)(ws + 58720256);   // 16.8 MB   V^T bf16 [B,H,64,S]
  u16* vals  = (u16*)(ws + 75497472);   // 16.8 MB   attn out bf16 (reshaped layout)
  u16* maskb = (u16*)(ws + 92274688);   // 67.1 MB   mask bf16 (optional)
  int use_mb = (ws_size >= 159383552ull) ? 1 : 0;

  cvt_f32_bf16<<<dim3(2048), dim3(256), 0, stream>>>(x, xb, (size_t)8388608);
  if (use_mb)
    cvt_f32_bf16<<<dim3(4096), dim3(256), 0, stream>>>(mask, maskb, (size_t)33554432);
  transpose_cvt<<<dim3(768), dim3(256), 0, stream>>>(Wqkv, wqkvT, 1024, 3072);
  transpose_cvt<<<dim3(256), dim3(256), 0, stream>>>(Wo, woT, 1024, 1024);

  gemm128<0><<<dim3(1536), dim3(256), 0, stream>>>(xb, wqkvT, bqkv, (void*)qb, kb, vT,
                                                   3072, 1024, 24);
  attn_kernel<<<dim3(2048), dim3(256), 0, stream>>>(qb, kb, vT,
      use_mb ? (const void*)maskb : (const void*)mask, use_mb, vals);
  gemm128<1><<<dim3(512), dim3(256), 0, stream>>>(vals, woT, bo, (void*)out, nullptr, nullptr,
                                                  1024, 1024, 8);
}

// Round 2
// 464.648 us; speedup vs baseline: 1.3315x; 1.3315x over previous
//
#include <hip/hip_runtime.h>
#include <hip/hip_bf16.h>

#define DEV __device__ __forceinline__

typedef unsigned short u16;
typedef __attribute__((ext_vector_type(4))) float f32x4;
typedef __attribute__((ext_vector_type(8))) short s16x8;

// problem constants
static constexpr int Bc = 2, Hc = 16, Sc = 4096, Dc = 1024, HDc = 64;

DEV u16 f2bf(float f) {
  unsigned x = __float_as_uint(f);
  x += 0x7FFFu + ((x >> 16) & 1u);   // RNE
  return (u16)(x >> 16);
}
DEV u16 f2bf_rn(float f) {            // fast round-to-nearest (2 ops)
  return (u16)((__float_as_uint(f) + 0x8000u) >> 16);
}
DEV float bf2f(u16 u) { return __uint_as_float(((unsigned)u) << 16); }

DEV void gload_lds16(const void* g, void* l) {
  __builtin_amdgcn_global_load_lds((const __attribute__((address_space(1))) void*)g,
                                   (__attribute__((address_space(3))) void*)l, 16, 0, 0);
}

DEV f32x4 mfma16(s16x8 a, s16x8 b, f32x4 c) {
  return __builtin_amdgcn_mfma_f32_16x16x32_bf16(a, b, c, 0, 0, 0);
}

DEV f32x4 fzero4() { f32x4 v; v[0] = v[1] = v[2] = v[3] = 0.f; return v; }

// ---------------- elementwise f32 -> bf16 (with optional scale) ----------------
__global__ void cvt_f32_bf16(const float* __restrict__ in, u16* __restrict__ out, size_t n,
                             float scale) {
  size_t i = ((size_t)blockIdx.x * blockDim.x + threadIdx.x) * 4;
  size_t stride = (size_t)gridDim.x * blockDim.x * 4;
  for (; i < n; i += stride) {
    float4 v = *(const float4*)(in + i);
    u16 a = f2bf(v.x * scale), b = f2bf(v.y * scale), c = f2bf(v.z * scale), d = f2bf(v.w * scale);
    *(ushort4*)(out + i) = make_ushort4(a, b, c, d);
  }
}

// ---------------- transpose + convert: out[c][r] = bf16(in[r][c]) ----------------
__global__ void transpose_cvt(const float* __restrict__ in, u16* __restrict__ out, int R, int C) {
  __shared__ u16 t[64][72];
  int nct = C >> 6;
  int tr = blockIdx.x / nct, tc = blockIdx.x % nct;
  int r0 = tr << 6, c0 = tc << 6;
  int lr = threadIdx.x >> 2;
  int lc0 = (threadIdx.x & 3) << 4;
  const float* src = in + (size_t)(r0 + lr) * C + c0 + lc0;
#pragma unroll
  for (int j = 0; j < 16; j += 4) {
    float4 v = *(const float4*)(src + j);
    t[lr][lc0 + j + 0] = f2bf(v.x);
    t[lr][lc0 + j + 1] = f2bf(v.y);
    t[lr][lc0 + j + 2] = f2bf(v.z);
    t[lr][lc0 + j + 3] = f2bf(v.w);
  }
  __syncthreads();
  u16* dst = out + (size_t)(c0 + lr) * R + r0 + lc0;
#pragma unroll
  for (int j = 0; j < 16; j += 4) {
    u16 a = t[lc0 + j + 0][lr], b = t[lc0 + j + 1][lr], c = t[lc0 + j + 2][lr], d = t[lc0 + j + 3][lr];
    *(ushort4*)(dst + j) = make_ushort4(a, b, c, d);
  }
}

// ---------------- GEMM: C[m][n] = A[m][:] . BT[n][:] + bias[n] ----------------
template <int MODE>
__global__ __launch_bounds__(256, 2) void gemm128(
    const u16* __restrict__ A, const u16* __restrict__ BT, const float* __restrict__ bias,
    void* __restrict__ out0, u16* __restrict__ out1, u16* __restrict__ out2,
    int N, int K, int grid_n) {
  __shared__ u16 Al[128 * 64];
  __shared__ u16 Bl[128 * 64];
  int bid = blockIdx.x;
  int bn = bid % grid_n, bm = bid / grid_n;
  int m0 = bm * 128, n0 = bn * 128;
  int tid = threadIdx.x, lane = tid & 63, wid = tid >> 6;
  int wm = wid >> 1, wn = wid & 1;
  int fr = lane & 15, fg = lane >> 4;

  f32x4 acc[4][4];
#pragma unroll
  for (int mi = 0; mi < 4; ++mi)
#pragma unroll
    for (int ni = 0; ni < 4; ++ni) acc[mi][ni] = fzero4();

  for (int kt = 0; kt < K; kt += 64) {
    const u16* Ag = A + (size_t)m0 * K + kt;
    const u16* Bg = BT + (size_t)n0 * K + kt;
#pragma unroll
    for (int it = 0; it < 4; ++it) {
      int L = it * 4096 + wid * 1024 + lane * 16;  // byte offset in 16KB tile
      int row = L >> 7;
      int sch = ((L >> 4) & 7) ^ (row & 7);
      gload_lds16(Ag + (size_t)row * K + sch * 8, (char*)Al + it * 4096 + wid * 1024);
      gload_lds16(Bg + (size_t)row * K + sch * 8, (char*)Bl + it * 4096 + wid * 1024);
    }
    __syncthreads();
#pragma unroll
    for (int c = 0; c < 2; ++c) {
      s16x8 af[4], bfr[4];
#pragma unroll
      for (int mi = 0; mi < 4; ++mi) {
        int row = wm * 64 + mi * 16 + fr;
        int ch = (c * 4 + fg) ^ (row & 7);
        af[mi] = *(const s16x8*)((const char*)Al + row * 128 + ch * 16);
      }
#pragma unroll
      for (int ni = 0; ni < 4; ++ni) {
        int row = wn * 64 + ni * 16 + fr;
        int ch = (c * 4 + fg) ^ (row & 7);
        bfr[ni] = *(const s16x8*)((const char*)Bl + row * 128 + ch * 16);
      }
#pragma unroll
      for (int mi = 0; mi < 4; ++mi)
#pragma unroll
        for (int ni = 0; ni < 4; ++ni) acc[mi][ni] = mfma16(af[mi], bfr[ni], acc[mi][ni]);
    }
    __syncthreads();
  }

  if constexpr (MODE == 0) {
    u16* qb = (u16*)out0;
    u16* kb = out1;
    u16* vT = out2;
#pragma unroll
    for (int ni = 0; ni < 4; ++ni) {
      int n = n0 + wn * 64 + ni * 16 + fr;
      float bv = bias[n];
      int h = n / 192;
      int c = n % 192;
      int part = c >> 6;
      int e = c & 63;
#pragma unroll
      for (int mi = 0; mi < 4; ++mi) {
        int m = m0 + wm * 64 + mi * 16 + fg * 4;
        int b = m >> 12;
        int s = m & 4095;
        size_t bh = (size_t)b * Hc + h;
        if (part == 2) {
          u16 a0 = f2bf(acc[mi][ni][0] + bv), a1 = f2bf(acc[mi][ni][1] + bv);
          u16 a2 = f2bf(acc[mi][ni][2] + bv), a3 = f2bf(acc[mi][ni][3] + bv);
          *(ushort4*)(vT + ((bh * HDc + e) * (size_t)Sc + s)) = make_ushort4(a0, a1, a2, a3);
        } else {
          u16* dst = (part == 0 ? qb : kb) + ((bh * Sc + s) * (size_t)HDc + e);
#pragma unroll
          for (int r = 0; r < 4; ++r) dst[(size_t)r * HDc] = f2bf(acc[mi][ni][r] + bv);
        }
      }
    }
  } else {
    float* O = (float*)out0;
#pragma unroll
    for (int ni = 0; ni < 4; ++ni) {
      int n = n0 + wn * 64 + ni * 16 + fr;
      float bv = bias[n];
#pragma unroll
      for (int mi = 0; mi < 4; ++mi) {
        int m = m0 + wm * 64 + mi * 16 + fg * 4;
#pragma unroll
        for (int r = 0; r < 4; ++r) O[(size_t)(m + r) * N + n] = acc[mi][ni][r] + bv;
      }
    }
  }
}

// ---------------- flash attention (swapped QK^T: scores/O transposed, q lane-local) ----
// grid: 2048 = (qt[64], b[2], h[16]) ; h fastest for mask L2 reuse.
// block: 256 threads = 4 waves, each wave owns 16 q-rows of a 64-row q-tile.
// Lane (fr,fg) owns q-row q0+wid*16+fr; holds scores for keys f*16+fg*4+r.
__global__ __launch_bounds__(256, 2) void attn_kernel(
    const u16* __restrict__ qb, const u16* __restrict__ kb, const u16* __restrict__ vT,
    const void* __restrict__ maskp, int mask_is_bf16, u16* __restrict__ vals) {
  __shared__ u16 Kl[64 * 64];
  __shared__ u16 Vl[64 * 64];
  __shared__ char Pl[4 * 16 * 144];   // per-wave [16 q][64 keys] bf16, 144B padded rows
  int bid = blockIdx.x;
  int h = bid & 15, b = (bid >> 4) & 1, qt = bid >> 5;
  int lane = threadIdx.x & 63, wid = threadIdx.x >> 6;
  int fr = lane & 15, fg = lane >> 4;
  size_t bh = (size_t)b * Hc + h;
  int q0 = qt * 64;
  int q = q0 + wid * 16 + fr;      // this lane's q-row

  // Q fragment (B-operand of swapped QK^T): Q[q][k = c*32 + fg*8 + i]
  const u16* Qrow = qb + ((bh * Sc) + q) * (size_t)HDc;
  s16x8 qa0 = *(const s16x8*)(Qrow + fg * 8);
  s16x8 qa1 = *(const s16x8*)(Qrow + 32 + fg * 8);

  f32x4 o[4];                       // o[ef][r] = O[e=ef*16+fg*4+r][q]
#pragma unroll
  for (int ef = 0; ef < 4; ++ef) o[ef] = fzero4();
  float mrun = -1e30f, lrun = 0.f;  // per-lane (one q-row), log2 domain

  const u16* Kg = kb + bh * (size_t)Sc * HDc;
  const u16* Vg = vT + bh * (size_t)HDc * Sc;
  char* pw = (char*)Pl + wid * 2304 + fr * 144;
  const float SCALE2 = 0.125f * 1.44269504088896340736f;  // scale * log2(e)
  const float LOG2E = 1.44269504088896340736f;

  // LDS read chunk index (same for K and V tiles, XOR-8 swizzled)
  int ch0 = (0 * 4 + fg) ^ (fr & 7);
  int ch1 = (1 * 4 + fg) ^ (fr & 7);

  const u16* mk_b = (const u16*)maskp + ((size_t)b * Sc + q) * Sc;
  const float* mk_f = (const float*)maskp + ((size_t)b * Sc + q) * Sc;

  for (int kt = 0; kt < Sc / 64; ++kt) {
    // stage K-tile [64 keys][64 e] and V^T-tile [64 e][64 keys], XOR-8 swizzled
#pragma unroll
    for (int it = 0; it < 2; ++it) {
      int L = it * 4096 + wid * 1024 + lane * 16;
      int row = L >> 7;
      int sch = ((L >> 4) & 7) ^ (row & 7);
      gload_lds16(Kg + ((size_t)(kt * 64 + row)) * HDc + sch * 8, (char*)Kl + it * 4096 + wid * 1024);
      gload_lds16(Vg + (size_t)row * Sc + kt * 64 + sch * 8, (char*)Vl + it * 4096 + wid * 1024);
    }
    __syncthreads();

    // mask loads first (latency hides under QK^T): 4 keys per fragment, consecutive
    ushort4 m4[4];
    float4 mf[4];
    if (mask_is_bf16) {
#pragma unroll
      for (int f = 0; f < 4; ++f)
        m4[f] = *(const ushort4*)(mk_b + kt * 64 + f * 16 + fg * 4);
    } else {
#pragma unroll
      for (int f = 0; f < 4; ++f)
        mf[f] = *(const float4*)(mk_f + kt * 64 + f * 16 + fg * 4);
    }

    // swapped QK^T: sa[f][r] = S[key = f*16+fg*4+r][q]
    f32x4 sa[4];
#pragma unroll
    for (int f = 0; f < 4; ++f) sa[f] = fzero4();
#pragma unroll
    for (int c = 0; c < 2; ++c) {
      s16x8 qa = (c == 0) ? qa0 : qa1;
      int ch = (c == 0) ? ch0 : ch1;
#pragma unroll
      for (int f = 0; f < 4; ++f) {
        s16x8 kf = *(const s16x8*)((const char*)Kl + (f * 16 + fr) * 128 + ch * 16);
        sa[f] = mfma16(kf, qa, sa[f]);
      }
    }

    // scale + mask (log2 domain)
    float sv[4][4];
    if (mask_is_bf16) {
#pragma unroll
      for (int f = 0; f < 4; ++f) {
        sv[f][0] = fmaf(sa[f][0], SCALE2, bf2f(m4[f].x));
        sv[f][1] = fmaf(sa[f][1], SCALE2, bf2f(m4[f].y));
        sv[f][2] = fmaf(sa[f][2], SCALE2, bf2f(m4[f].z));
        sv[f][3] = fmaf(sa[f][3], SCALE2, bf2f(m4[f].w));
      }
    } else {
#pragma unroll
      for (int f = 0; f < 4; ++f) {
        sv[f][0] = fmaf(sa[f][0], SCALE2, mf[f].x * LOG2E);
        sv[f][1] = fmaf(sa[f][1], SCALE2, mf[f].y * LOG2E);
        sv[f][2] = fmaf(sa[f][2], SCALE2, mf[f].z * LOG2E);
        sv[f][3] = fmaf(sa[f][3], SCALE2, mf[f].w * LOG2E);
      }
    }

    // online softmax, per-lane row; cross-lane only over fg (d=16,32)
    float mt = fmaxf(fmaxf(fmaxf(sv[0][0], sv[0][1]), fmaxf(sv[0][2], sv[0][3])),
                     fmaxf(fmaxf(sv[1][0], sv[1][1]), fmaxf(sv[1][2], sv[1][3])));
    float mt2 = fmaxf(fmaxf(fmaxf(sv[2][0], sv[2][1]), fmaxf(sv[2][2], sv[2][3])),
                      fmaxf(fmaxf(sv[3][0], sv[3][1]), fmaxf(sv[3][2], sv[3][3])));
    mt = fmaxf(mt, mt2);
    mt = fmaxf(mt, __shfl_xor(mt, 16, 64));
    mt = fmaxf(mt, __shfl_xor(mt, 32, 64));
    float mnew = fmaxf(mrun, mt);
    float alph = __builtin_amdgcn_exp2f(mrun - mnew);
    mrun = mnew;

    float p[4][4];
    float ssum = 0.f;
#pragma unroll
    for (int f = 0; f < 4; ++f) {
      float s0 = __builtin_amdgcn_exp2f(sv[f][0] - mnew);
      float s1 = __builtin_amdgcn_exp2f(sv[f][1] - mnew);
      float s2 = __builtin_amdgcn_exp2f(sv[f][2] - mnew);
      float s3 = __builtin_amdgcn_exp2f(sv[f][3] - mnew);
      p[f][0] = s0; p[f][1] = s1; p[f][2] = s2; p[f][3] = s3;
      ssum += (s0 + s1) + (s2 + s3);
    }
    ssum += __shfl_xor(ssum, 16, 64);
    ssum += __shfl_xor(ssum, 32, 64);
    lrun = fmaf(lrun, alph, ssum);

#pragma unroll
    for (int ef = 0; ef < 4; ++ef) o[ef] *= alph;

    // P -> per-wave LDS [16 q][64 keys] bf16 (144B row pad = conflict-free)
#pragma unroll
    for (int f = 0; f < 4; ++f) {
      ushort4 pk = make_ushort4(f2bf_rn(p[f][0]), f2bf_rn(p[f][1]),
                                f2bf_rn(p[f][2]), f2bf_rn(p[f][3]));
      *(ushort4*)(pw + f * 32 + fg * 8) = pk;
    }

    // PV: O^T[e][q] += V^T[e][k] * P[q][k]
#pragma unroll
    for (int c = 0; c < 2; ++c) {
      s16x8 pa = *(const s16x8*)(pw + c * 64 + fg * 16);
      int ch = (c == 0) ? ch0 : ch1;
#pragma unroll
      for (int ef = 0; ef < 4; ++ef) {
        s16x8 vf = *(const s16x8*)((const char*)Vl + (ef * 16 + fr) * 128 + ch * 16);
        o[ef] = mfma16(vf, pa, o[ef]);
      }
    }
    __syncthreads();
  }

  // epilogue: normalize + store to vals in [B,H,S,HD]-flat order
  float inv = 1.f / lrun;
  u16* vbase = vals + (size_t)b * Sc * Dc + (size_t)h * Sc * HDc + (size_t)q * HDc;
#pragma unroll
  for (int ef = 0; ef < 4; ++ef) {
    ushort4 ov = make_ushort4(f2bf(o[ef][0] * inv), f2bf(o[ef][1] * inv),
                              f2bf(o[ef][2] * inv), f2bf(o[ef][3] * inv));
    *(ushort4*)(vbase + ef * 16 + fg * 4) = ov;
  }
}

extern "C" void kernel_launch(void* const* d_in, const int* in_sizes, int n_in,
                              void* d_out, int out_size, void* d_ws, size_t ws_size,
                              hipStream_t stream) {
  (void)in_sizes; (void)n_in; (void)out_size;
  const float* x    = (const float*)d_in[0];
  const float* mask = (const float*)d_in[1];
  const float* Wqkv = (const float*)d_in[2];
  const float* bqkv = (const float*)d_in[3];
  const float* Wo   = (const float*)d_in[4];
  const float* bo   = (const float*)d_in[5];
  float* out = (float*)d_out;
  char* ws = (char*)d_ws;

  u16* xb    = (u16*)(ws + 0);          // 16.8 MB   x as bf16 [8192][1024]
  u16* wqkvT = (u16*)(ws + 16777216);   // 6.3 MB    Wqkv^T bf16 [3072][1024]
  u16* woT   = (u16*)(ws + 23068672);   // 2.1 MB    Wo^T bf16 [1024][1024]
  u16* qb    = (u16*)(ws + 25165824);   // 16.8 MB   Q bf16 [B,H,S,64]
  u16* kb    = (u16*)(ws + 41943040);   // 16.8 MB   K bf16 [B,H,S,64]
  u16* vT    = (u16*)(ws + 58720256);   // 16.8 MB   V^T bf16 [B,H,64,S]
  u16* vals  = (u16*)(ws + 75497472);   // 16.8 MB   attn out bf16 (reshaped layout)
  u16* maskb = (u16*)(ws + 92274688);   // 67.1 MB   mask bf16 * LOG2E (optional)
  int use_mb = (ws_size >= 159383552ull) ? 1 : 0;
  const float LOG2E = 1.44269504088896340736f;

  cvt_f32_bf16<<<dim3(2048), dim3(256), 0, stream>>>(x, xb, (size_t)8388608, 1.0f);
  if (use_mb)
    cvt_f32_bf16<<<dim3(4096), dim3(256), 0, stream>>>(mask, maskb, (size_t)33554432, LOG2E);
  transpose_cvt<<<dim3(768), dim3(256), 0, stream>>>(Wqkv, wqkvT, 1024, 3072);
  transpose_cvt<<<dim3(256), dim3(256), 0, stream>>>(Wo, woT, 1024, 1024);

  gemm128<0><<<dim3(1536), dim3(256), 0, stream>>>(xb, wqkvT, bqkv, (void*)qb, kb, vT,
                                                   3072, 1024, 24);
  attn_kernel<<<dim3(2048), dim3(256), 0, stream>>>(qb, kb, vT,
      use_mb ? (const void*)maskb : (const void*)mask, use_mb, vals);
  gemm128<1><<<dim3(512), dim3(256), 0, stream>>>(vals, woT, bo, (void*)out, nullptr, nullptr,
                                                  1024, 1024, 8);
}

// Round 3
// 451.713 us; speedup vs baseline: 1.3696x; 1.0286x over previous
//
#include <hip/hip_runtime.h>
#include <hip/hip_bf16.h>

#define DEV __device__ __forceinline__

typedef unsigned short u16;
typedef __attribute__((ext_vector_type(4))) float f32x4;
typedef __attribute__((ext_vector_type(8))) short s16x8;

// problem constants
static constexpr int Bc = 2, Hc = 16, Sc = 4096, Dc = 1024, HDc = 64;

DEV u16 f2bf(float f) {
  unsigned x = __float_as_uint(f);
  x += 0x7FFFu + ((x >> 16) & 1u);   // RNE
  return (u16)(x >> 16);
}
DEV float bf2f(u16 u) { return __uint_as_float(((unsigned)u) << 16); }

DEV unsigned cvtpk_bf16(float lo, float hi) {   // word = bf16(lo) | bf16(hi)<<16
  unsigned r;
  asm("v_cvt_pk_bf16_f32 %0, %1, %2" : "=v"(r) : "v"(lo), "v"(hi));
  return r;
}

DEV void gload_lds16(const void* g, void* l) {
  __builtin_amdgcn_global_load_lds((const __attribute__((address_space(1))) void*)g,
                                   (__attribute__((address_space(3))) void*)l, 16, 0, 0);
}

DEV f32x4 mfma16(s16x8 a, s16x8 b, f32x4 c) {
  return __builtin_amdgcn_mfma_f32_16x16x32_bf16(a, b, c, 0, 0, 0);
}

DEV f32x4 fzero4() { f32x4 v; v[0] = v[1] = v[2] = v[3] = 0.f; return v; }

// ---------------- elementwise f32 -> bf16 ----------------
__global__ void cvt_f32_bf16(const float* __restrict__ in, u16* __restrict__ out, size_t n) {
  size_t i = ((size_t)blockIdx.x * blockDim.x + threadIdx.x) * 4;
  size_t stride = (size_t)gridDim.x * blockDim.x * 4;
  for (; i < n; i += stride) {
    float4 v = *(const float4*)(in + i);
    u16 a = f2bf(v.x), b = f2bf(v.y), c = f2bf(v.z), d = f2bf(v.w);
    *(ushort4*)(out + i) = make_ushort4(a, b, c, d);
  }
}

// ---------------- transpose + convert: out[c][r] = bf16(in[r][c]) ----------------
__global__ void transpose_cvt(const float* __restrict__ in, u16* __restrict__ out, int R, int C) {
  __shared__ u16 t[64][72];
  int nct = C >> 6;
  int tr = blockIdx.x / nct, tc = blockIdx.x % nct;
  int r0 = tr << 6, c0 = tc << 6;
  int lr = threadIdx.x >> 2;
  int lc0 = (threadIdx.x & 3) << 4;
  const float* src = in + (size_t)(r0 + lr) * C + c0 + lc0;
#pragma unroll
  for (int j = 0; j < 16; j += 4) {
    float4 v = *(const float4*)(src + j);
    t[lr][lc0 + j + 0] = f2bf(v.x);
    t[lr][lc0 + j + 1] = f2bf(v.y);
    t[lr][lc0 + j + 2] = f2bf(v.z);
    t[lr][lc0 + j + 3] = f2bf(v.w);
  }
  __syncthreads();
  u16* dst = out + (size_t)(c0 + lr) * R + r0 + lc0;
#pragma unroll
  for (int j = 0; j < 16; j += 4) {
    u16 a = t[lc0 + j + 0][lr], b = t[lc0 + j + 1][lr], c = t[lc0 + j + 2][lr], d = t[lc0 + j + 3][lr];
    *(ushort4*)(dst + j) = make_ushort4(a, b, c, d);
  }
}

// ---------------- GEMM: C[m][n] = A[m][:] . BT[n][:] + bias[n] ----------------
template <int MODE>
__global__ __launch_bounds__(256, 2) void gemm128(
    const u16* __restrict__ A, const u16* __restrict__ BT, const float* __restrict__ bias,
    void* __restrict__ out0, u16* __restrict__ out1, u16* __restrict__ out2,
    int N, int K, int grid_n) {
  __shared__ u16 Al[128 * 64];
  __shared__ u16 Bl[128 * 64];
  int bid = blockIdx.x;
  int bn = bid % grid_n, bm = bid / grid_n;
  int m0 = bm * 128, n0 = bn * 128;
  int tid = threadIdx.x, lane = tid & 63, wid = tid >> 6;
  int wm = wid >> 1, wn = wid & 1;
  int fr = lane & 15, fg = lane >> 4;

  f32x4 acc[4][4];
#pragma unroll
  for (int mi = 0; mi < 4; ++mi)
#pragma unroll
    for (int ni = 0; ni < 4; ++ni) acc[mi][ni] = fzero4();

  for (int kt = 0; kt < K; kt += 64) {
    const u16* Ag = A + (size_t)m0 * K + kt;
    const u16* Bg = BT + (size_t)n0 * K + kt;
#pragma unroll
    for (int it = 0; it < 4; ++it) {
      int L = it * 4096 + wid * 1024 + lane * 16;  // byte offset in 16KB tile
      int row = L >> 7;
      int sch = ((L >> 4) & 7) ^ (row & 7);
      gload_lds16(Ag + (size_t)row * K + sch * 8, (char*)Al + it * 4096 + wid * 1024);
      gload_lds16(Bg + (size_t)row * K + sch * 8, (char*)Bl + it * 4096 + wid * 1024);
    }
    __syncthreads();
#pragma unroll
    for (int c = 0; c < 2; ++c) {
      s16x8 af[4], bfr[4];
#pragma unroll
      for (int mi = 0; mi < 4; ++mi) {
        int row = wm * 64 + mi * 16 + fr;
        int ch = (c * 4 + fg) ^ (row & 7);
        af[mi] = *(const s16x8*)((const char*)Al + row * 128 + ch * 16);
      }
#pragma unroll
      for (int ni = 0; ni < 4; ++ni) {
        int row = wn * 64 + ni * 16 + fr;
        int ch = (c * 4 + fg) ^ (row & 7);
        bfr[ni] = *(const s16x8*)((const char*)Bl + row * 128 + ch * 16);
      }
#pragma unroll
      for (int mi = 0; mi < 4; ++mi)
#pragma unroll
        for (int ni = 0; ni < 4; ++ni) acc[mi][ni] = mfma16(af[mi], bfr[ni], acc[mi][ni]);
    }
    __syncthreads();
  }

  if constexpr (MODE == 0) {
    u16* qb = (u16*)out0;
    u16* kb = out1;
    u16* vT = out2;
#pragma unroll
    for (int ni = 0; ni < 4; ++ni) {
      int n = n0 + wn * 64 + ni * 16 + fr;
      float bv = bias[n];
      int h = n / 192;
      int c = n % 192;
      int part = c >> 6;
      int e = c & 63;
#pragma unroll
      for (int mi = 0; mi < 4; ++mi) {
        int m = m0 + wm * 64 + mi * 16 + fg * 4;
        int b = m >> 12;
        int s = m & 4095;
        size_t bh = (size_t)b * Hc + h;
        if (part == 2) {
          u16 a0 = f2bf(acc[mi][ni][0] + bv), a1 = f2bf(acc[mi][ni][1] + bv);
          u16 a2 = f2bf(acc[mi][ni][2] + bv), a3 = f2bf(acc[mi][ni][3] + bv);
          *(ushort4*)(vT + ((bh * HDc + e) * (size_t)Sc + s)) = make_ushort4(a0, a1, a2, a3);
        } else {
          u16* dst = (part == 0 ? qb : kb) + ((bh * Sc + s) * (size_t)HDc + e);
#pragma unroll
          for (int r = 0; r < 4; ++r) dst[(size_t)r * HDc] = f2bf(acc[mi][ni][r] + bv);
        }
      }
    }
  } else {
    float* O = (float*)out0;
#pragma unroll
    for (int ni = 0; ni < 4; ++ni) {
      int n = n0 + wn * 64 + ni * 16 + fr;
      float bv = bias[n];
#pragma unroll
      for (int mi = 0; mi < 4; ++mi) {
        int m = m0 + wm * 64 + mi * 16 + fg * 4;
#pragma unroll
        for (int r = 0; r < 4; ++r) O[(size_t)(m + r) * N + n] = acc[mi][ni][r] + bv;
      }
    }
  }
}

// ---------------- flash attention (swapped QK^T, double-buffered K/V, defer-max) ----
// 2048 blocks; XCD-bijective swizzle so the 16 h-blocks of one (b,qt) share an XCD L2.
// block: 256 threads = 4 waves; lane (fr,fg) owns q-row q0+wid*16+fr,
// holds scores for keys f*16+fg*4+r.
__global__ __launch_bounds__(256, 2) void attn_kernel(
    const u16* __restrict__ qb, const u16* __restrict__ kb, const u16* __restrict__ vT,
    const float* __restrict__ maskp, u16* __restrict__ vals) {
  __shared__ u16 Kl[2][64 * 64];     // 2 x 8KB
  __shared__ u16 Vl[2][64 * 64];     // 2 x 8KB
  __shared__ char Pl[4 * 16 * 144];  // per-wave [16 q][64 k] bf16, 144B rows

  // XCD-bijective swizzle: physical blockIdx p*8+x -> logical x*256+p
  int bid = ((blockIdx.x & 7) << 8) | (blockIdx.x >> 3);
  int h = bid & 15, b = (bid >> 4) & 1, qt = bid >> 5;
  int lane = threadIdx.x & 63, wid = threadIdx.x >> 6;
  int fr = lane & 15, fg = lane >> 4;
  size_t bh = (size_t)b * Hc + h;
  int q0 = qt * 64;
  int q = q0 + wid * 16 + fr;      // this lane's q-row

  // Q fragment (B-operand of swapped QK^T): Q[q][k = c*32 + fg*8 + i]
  const u16* Qrow = qb + ((bh * Sc) + q) * (size_t)HDc;
  s16x8 qa0 = *(const s16x8*)(Qrow + fg * 8);
  s16x8 qa1 = *(const s16x8*)(Qrow + 32 + fg * 8);

  f32x4 o[4];                       // o[ef][r] = O[e=ef*16+fg*4+r][q]
#pragma unroll
  for (int ef = 0; ef < 4; ++ef) o[ef] = fzero4();
  float mrun = -1e30f, lrun = 0.f;

  const u16* Kg = kb + bh * (size_t)Sc * HDc;
  const u16* Vg = vT + bh * (size_t)HDc * Sc;
  char* pw = (char*)Pl + wid * 2304 + fr * 144;
  const float SCALE = 0.125f;
  const float LOG2E = 1.44269504088896340736f;

  // staging addresses (pre-swizzled global source, linear LDS dest)
  int L0 = wid * 1024 + lane * 16;
  int L1 = 4096 + wid * 1024 + lane * 16;
  int row0 = L0 >> 7, row1 = L1 >> 7;
  int sch0s = ((L0 >> 4) & 7) ^ (row0 & 7);
  int sch1s = ((L1 >> 4) & 7) ^ (row1 & 7);
  const u16* KgS0 = Kg + (size_t)row0 * HDc + sch0s * 8;
  const u16* KgS1 = Kg + (size_t)row1 * HDc + sch1s * 8;
  const u16* VgS0 = Vg + (size_t)row0 * Sc + sch0s * 8;
  const u16* VgS1 = Vg + (size_t)row1 * Sc + sch1s * 8;
  int ldsA = wid * 1024;            // byte offset for it=0 chunk
  int ldsB = 4096 + wid * 1024;     // byte offset for it=1 chunk

  // fragment-read byte offsets (XOR-8 swizzled chunks)
  int ch0 = fg ^ (fr & 7);
  int ch1 = (4 + fg) ^ (fr & 7);
  int kroff0 = fr * 128 + ch0 * 16;
  int kroff1 = fr * 128 + ch1 * 16;

  const float* mk = maskp + ((size_t)b * Sc + q) * Sc;

  // prologue: stage tile 0 into buffer 0
  gload_lds16(KgS0, (char*)Kl[0] + ldsA);
  gload_lds16(KgS1, (char*)Kl[0] + ldsB);
  gload_lds16(VgS0, (char*)Vl[0] + ldsA);
  gload_lds16(VgS1, (char*)Vl[0] + ldsB);
  __syncthreads();

  for (int kt = 0; kt < Sc / 64; ++kt) {
    int cur = kt & 1;
    // stage tile kt+1 into the other buffer (loads fly during compute)
    if (kt < Sc / 64 - 1) {
      int nxt = cur ^ 1;
      size_t ko = (size_t)(kt + 1) * 64 * HDc;
      size_t vo = (size_t)(kt + 1) * 64;
      gload_lds16(KgS0 + ko, (char*)Kl[nxt] + ldsA);
      gload_lds16(KgS1 + ko, (char*)Kl[nxt] + ldsB);
      gload_lds16(VgS0 + vo, (char*)Vl[nxt] + ldsA);
      gload_lds16(VgS1 + vo, (char*)Vl[nxt] + ldsB);
    }

    // mask loads (f32, latency hides under QK^T)
    const float* mrow = mk + kt * 64 + fg * 4;
    float4 mf0 = *(const float4*)(mrow);
    float4 mf1 = *(const float4*)(mrow + 16);
    float4 mf2 = *(const float4*)(mrow + 32);
    float4 mf3 = *(const float4*)(mrow + 48);

    // swapped QK^T: sa[f][r] = S[key = f*16+fg*4+r][q]
    const char* Kc = (const char*)Kl[cur];
    f32x4 sa[4];
#pragma unroll
    for (int f = 0; f < 4; ++f) sa[f] = fzero4();
    __builtin_amdgcn_s_setprio(1);
#pragma unroll
    for (int f = 0; f < 4; ++f) {
      s16x8 kf = *(const s16x8*)(Kc + f * 2048 + kroff0);
      sa[f] = mfma16(kf, qa0, sa[f]);
    }
#pragma unroll
    for (int f = 0; f < 4; ++f) {
      s16x8 kf = *(const s16x8*)(Kc + f * 2048 + kroff1);
      sa[f] = mfma16(kf, qa1, sa[f]);
    }
    __builtin_amdgcn_s_setprio(0);

    // scale + mask (natural domain)
    float t[4][4];
#pragma unroll
    for (int r = 0; r < 4; ++r) {
      t[0][r] = fmaf(sa[0][r], SCALE, (&mf0.x)[r]);
      t[1][r] = fmaf(sa[1][r], SCALE, (&mf1.x)[r]);
      t[2][r] = fmaf(sa[2][r], SCALE, (&mf2.x)[r]);
      t[3][r] = fmaf(sa[3][r], SCALE, (&mf3.x)[r]);
    }

    // tile max (max3-fusable tree) + cross-lane over fg groups
    float x0 = fmaxf(fmaxf(t[0][0], t[0][1]), t[0][2]);
    float x1 = fmaxf(fmaxf(t[0][3], t[1][0]), t[1][1]);
    float x2 = fmaxf(fmaxf(t[1][2], t[1][3]), t[2][0]);
    float x3 = fmaxf(fmaxf(t[2][1], t[2][2]), t[2][3]);
    float x4 = fmaxf(fmaxf(t[3][0], t[3][1]), t[3][2]);
    float mt = fmaxf(fmaxf(fmaxf(x0, x1), x2), fmaxf(fmaxf(x3, x4), t[3][3]));
    mt = fmaxf(mt, __shfl_xor(mt, 16, 64));
    mt = fmaxf(mt, __shfl_xor(mt, 32, 64));

    // defer-max: only rescale when the wave's max grew past threshold
    if (!__all(mt <= mrun + 8.0f)) {
      float mnew = fmaxf(mrun, mt);
      float al = __builtin_amdgcn_exp2f((mrun - mnew) * LOG2E);
      mrun = mnew;
      lrun *= al;
#pragma unroll
      for (int ef = 0; ef < 4; ++ef) o[ef] *= al;
    }

    float nm = -mrun * LOG2E;
    float p[4][4];
    float ss0 = 0.f, ss1 = 0.f;
#pragma unroll
    for (int f = 0; f < 4; ++f) {
      float p0 = __builtin_amdgcn_exp2f(fmaf(t[f][0], LOG2E, nm));
      float p1 = __builtin_amdgcn_exp2f(fmaf(t[f][1], LOG2E, nm));
      float p2 = __builtin_amdgcn_exp2f(fmaf(t[f][2], LOG2E, nm));
      float p3 = __builtin_amdgcn_exp2f(fmaf(t[f][3], LOG2E, nm));
      p[f][0] = p0; p[f][1] = p1; p[f][2] = p2; p[f][3] = p3;
      ss0 += (p0 + p1);
      ss1 += (p2 + p3);
    }
    float ssum = ss0 + ss1;
    ssum += __shfl_xor(ssum, 16, 64);
    ssum += __shfl_xor(ssum, 32, 64);
    lrun += ssum;

    // P -> per-wave LDS via packed cvt (8 words, 4x b64 stores)
#pragma unroll
    for (int f = 0; f < 4; ++f) {
      uint2 pk;
      pk.x = cvtpk_bf16(p[f][0], p[f][1]);
      pk.y = cvtpk_bf16(p[f][2], p[f][3]);
      *(uint2*)(pw + f * 32 + fg * 8) = pk;
    }

    // PV: O^T[e][q] += V^T[e][k] * P[q][k]
    const char* Vc = (const char*)Vl[cur];
    s16x8 pa0 = *(const s16x8*)(pw + fg * 16);
    s16x8 pa1 = *(const s16x8*)(pw + 64 + fg * 16);
    __builtin_amdgcn_s_setprio(1);
#pragma unroll
    for (int ef = 0; ef < 4; ++ef) {
      s16x8 vf = *(const s16x8*)(Vc + ef * 2048 + kroff0);
      o[ef] = mfma16(vf, pa0, o[ef]);
    }
#pragma unroll
    for (int ef = 0; ef < 4; ++ef) {
      s16x8 vf = *(const s16x8*)(Vc + ef * 2048 + kroff1);
      o[ef] = mfma16(vf, pa1, o[ef]);
    }
    __builtin_amdgcn_s_setprio(0);

    __syncthreads();   // drains vmcnt (stage of kt+1) + releases buffers
  }

  // epilogue: normalize + store to vals in [B,H,S,HD]-flat order
  float inv = 1.f / lrun;
  u16* vbase = vals + (size_t)b * Sc * Dc + (size_t)h * Sc * HDc + (size_t)q * HDc;
#pragma unroll
  for (int ef = 0; ef < 4; ++ef) {
    ushort4 ov = make_ushort4(f2bf(o[ef][0] * inv), f2bf(o[ef][1] * inv),
                              f2bf(o[ef][2] * inv), f2bf(o[ef][3] * inv));
    *(ushort4*)(vbase + ef * 16 + fg * 4) = ov;
  }
}

extern "C" void kernel_launch(void* const* d_in, const int* in_sizes, int n_in,
                              void* d_out, int out_size, void* d_ws, size_t ws_size,
                              hipStream_t stream) {
  (void)in_sizes; (void)n_in; (void)out_size; (void)ws_size;
  const float* x    = (const float*)d_in[0];
  const float* mask = (const float*)d_in[1];
  const float* Wqkv = (const float*)d_in[2];
  const float* bqkv = (const float*)d_in[3];
  const float* Wo   = (const float*)d_in[4];
  const float* bo   = (const float*)d_in[5];
  float* out = (float*)d_out;
  char* ws = (char*)d_ws;

  u16* xb    = (u16*)(ws + 0);          // 16.8 MB   x as bf16 [8192][1024]
  u16* wqkvT = (u16*)(ws + 16777216);   // 6.3 MB    Wqkv^T bf16 [3072][1024]
  u16* woT   = (u16*)(ws + 23068672);   // 2.1 MB    Wo^T bf16 [1024][1024]
  u16* qb    = (u16*)(ws + 25165824);   // 16.8 MB   Q bf16 [B,H,S,64]
  u16* kb    = (u16*)(ws + 41943040);   // 16.8 MB   K bf16 [B,H,S,64]
  u16* vT    = (u16*)(ws + 58720256);   // 16.8 MB   V^T bf16 [B,H,64,S]
  u16* vals  = (u16*)(ws + 75497472);   // 16.8 MB   attn out bf16 (reshaped layout)

  cvt_f32_bf16<<<dim3(2048), dim3(256), 0, stream>>>(x, xb, (size_t)8388608);
  transpose_cvt<<<dim3(768), dim3(256), 0, stream>>>(Wqkv, wqkvT, 1024, 3072);
  transpose_cvt<<<dim3(256), dim3(256), 0, stream>>>(Wo, woT, 1024, 1024);

  gemm128<0><<<dim3(1536), dim3(256), 0, stream>>>(xb, wqkvT, bqkv, (void*)qb, kb, vT,
                                                   3072, 1024, 24);
  attn_kernel<<<dim3(2048), dim3(256), 0, stream>>>(qb, kb, vT, mask, vals);
  gemm128<1><<<dim3(512), dim3(256), 0, stream>>>(vals, woT, bo, (void*)out, nullptr, nullptr,
                                                  1024, 1024, 8);
}